// Round 1
// baseline (30.114 us; speedup 1.0000x reference)
//
#include <hip/hip_runtime.h>

#define N_SAMPLES 32768
#define N_EVENTS 16
#define HOP 256
#define TILE 1024   // samples per block = 256 threads * 4

__global__ __launch_bounds__(256) void ola_gather_kernel(
    const float* __restrict__ x,     // (128, 16, 32768)
    const int* __restrict__ indices, // (128, 16)
    float* __restrict__ out)         // (128, 32768)
{
    const int tile = blockIdx.x & 31;        // 32 tiles per batch
    const int b    = blockIdx.x >> 5;
    const int s0   = tile * TILE + threadIdx.x * 4;

    const float* xb = x + (size_t)b * N_EVENTS * N_SAMPLES;
    const int*   ib = indices + b * N_EVENTS;

    float4 acc = make_float4(0.f, 0.f, 0.f, 0.f);

#pragma unroll
    for (int i = 0; i < N_EVENTS; ++i) {
        const int start = ib[i] * HOP;       // multiple of 256
        if (s0 >= start) {
            // s0 - start is a multiple of 4 -> 16B-aligned float4 load,
            // and (s0 - start) + 3 < N_SAMPLES, so always in bounds.
            const float4 v = *reinterpret_cast<const float4*>(
                xb + (size_t)i * N_SAMPLES + (s0 - start));
            acc.x += v.x; acc.y += v.y; acc.z += v.z; acc.w += v.w;
        }
    }

    *reinterpret_cast<float4*>(out + (size_t)b * N_SAMPLES + s0) = acc;
}

extern "C" void kernel_launch(void* const* d_in, const int* in_sizes, int n_in,
                              void* d_out, int out_size, void* d_ws, size_t ws_size,
                              hipStream_t stream) {
    const float* x       = (const float*)d_in[0];
    const int*   indices = (const int*)d_in[1];
    float*       out     = (float*)d_out;

    // 128 batches * (32768 / 1024) tiles = 4096 blocks
    const int blocks = 128 * (N_SAMPLES / TILE);
    ola_gather_kernel<<<blocks, 256, 0, stream>>>(x, indices, out);
}

// Round 2
// 30.024 us; speedup vs baseline: 1.0030x; 1.0030x over previous
//
#include <hip/hip_runtime.h>

#define N_SAMPLES 32768
#define N_EVENTS 16
#define HOP 256
#define TILE 1024   // samples per tile = 256 threads * 4

typedef float f32x4 __attribute__((ext_vector_type(4)));

__global__ __launch_bounds__(256) void ola_gather_kernel(
    const float* __restrict__ x,     // (128, 16, 32768)
    const int* __restrict__ indices, // (128, 16)
    float* __restrict__ out)         // (128, 32768)
{
    // Block handles batch b and the complementary tile pair (p, 31-p).
    // Work per block (= #events with start <= s) is ~constant across blocks,
    // eliminating CU-level load imbalance.
    const int p  = blockIdx.x >> 7;   // 0..15
    const int b  = blockIdx.x & 127;  // 0..127
    const int sA = p * TILE + threadIdx.x * 4;
    const int sB = (31 - p) * TILE + threadIdx.x * 4;

    const float* xb = x + (size_t)b * N_EVENTS * N_SAMPLES;
    const int*   ib = indices + b * N_EVENTS;

    f32x4 accA = (f32x4)0.f;
    f32x4 accB = (f32x4)0.f;

#pragma unroll
    for (int i = 0; i < N_EVENTS; ++i) {
        const int start = ib[i] * HOP;          // multiple of 256
        const float* row = xb + (size_t)i * N_SAMPLES;
        if (sA >= start) {
            // offset is a multiple of 4 -> 16B-aligned, always in bounds
            accA += __builtin_nontemporal_load(
                reinterpret_cast<const f32x4*>(row + (sA - start)));
        }
        if (sB >= start) {
            accB += __builtin_nontemporal_load(
                reinterpret_cast<const f32x4*>(row + (sB - start)));
        }
    }

    float* ob = out + (size_t)b * N_SAMPLES;
    __builtin_nontemporal_store(accA, reinterpret_cast<f32x4*>(ob + sA));
    __builtin_nontemporal_store(accB, reinterpret_cast<f32x4*>(ob + sB));
}

extern "C" void kernel_launch(void* const* d_in, const int* in_sizes, int n_in,
                              void* d_out, int out_size, void* d_ws, size_t ws_size,
                              hipStream_t stream) {
    const float* x       = (const float*)d_in[0];
    const int*   indices = (const int*)d_in[1];
    float*       out     = (float*)d_out;

    // 128 batches * 16 tile-pairs = 2048 blocks
    ola_gather_kernel<<<2048, 256, 0, stream>>>(x, indices, out);
}